// Round 10
// baseline (302.645 us; speedup 1.0000x reference)
//
#include <hip/hip_runtime.h>
#include <hip/hip_bf16.h>

typedef unsigned short u16;
typedef __attribute__((ext_vector_type(8))) short short8;
typedef __attribute__((ext_vector_type(4))) float f32x4;
typedef __attribute__((ext_vector_type(16))) float f32x16;
typedef __attribute__((ext_vector_type(4))) unsigned short u16x4;
typedef __attribute__((ext_vector_type(4))) int int4v;

#define S_LEN 2048
#define NH 32
#define NKV 8
// HD = 64, G = 4, D = 2048, M = B*S = 4096
// Q is pre-scaled by 0.125 * log2(e) so softmax runs in exp2 space.
#define QSCALE 0.18033688011112042f
// Fixed softmax shift (softmax is shift-invariant; |scores| << 14 always here)
#define PSHIFT 14.0f

__device__ __forceinline__ float fexp2(float x) { return __builtin_amdgcn_exp2f(x); }

__device__ __forceinline__ u16 f2bf(float f) {
  unsigned int u = __builtin_bit_cast(unsigned int, f);
  u += 0x7fffu + ((u >> 16) & 1u);
  return (u16)(u >> 16);
}

__device__ __forceinline__ unsigned int pk2bf(float a, float b) {
  float2 t; t.x = a; t.y = b;
  __hip_bfloat162 h = __float22bfloat162_rn(t);
  unsigned int r;
  __builtin_memcpy(&r, &h, 4);
  return r;
}

__device__ __forceinline__ void async16(const void* g, void* l) {
  __builtin_amdgcn_global_load_lds(
      (__attribute__((address_space(1))) void*)g,
      (__attribute__((address_space(3))) void*)l, 16, 0, 0);
}

__device__ __forceinline__ short8 mk_pf(unsigned a, unsigned b, unsigned c, unsigned d) {
  int4v t; t.x = (int)a; t.y = (int)b; t.z = (int)c; t.w = (int)d;
  return __builtin_bit_cast(short8, t);
}

// -------- prep: X cast (blocks 0..8191) + 4 weight transposes (8192..18431) --------
__global__ __launch_bounds__(256) void prep_kernel(const float* __restrict__ X,
                                                   const float* __restrict__ Wq,
                                                   const float* __restrict__ Wk,
                                                   const float* __restrict__ Wv,
                                                   const float* __restrict__ Wo,
                                                   u16* __restrict__ Xb,
                                                   u16* __restrict__ Wqt,
                                                   u16* __restrict__ Wkt,
                                                   u16* __restrict__ Wvt,
                                                   u16* __restrict__ Wot) {
  __shared__ float tile[32][33];
  int bx = blockIdx.x, tid = threadIdx.x;
  if (bx < 8192) {
    int idx = bx * 256 + tid;
    float4 v = ((const float4*)X)[idx];
    u16x4 o;
    o.x = f2bf(v.x); o.y = f2bf(v.y); o.z = f2bf(v.z); o.w = f2bf(v.w);
    *(u16x4*)&Xb[(size_t)idx * 4] = o;
    return;
  }
  const float* in; u16* out; int N, bi;
  if (bx < 12288)      { bi = bx - 8192;  in = Wq; out = Wqt; N = 2048; }
  else if (bx < 13312) { bi = bx - 12288; in = Wk; out = Wkt; N = 512; }
  else if (bx < 14336) { bi = bx - 13312; in = Wv; out = Wvt; N = 512; }
  else                 { bi = bx - 14336; in = Wo; out = Wot; N = 2048; }
  const int K = 2048;
  int nbx = N >> 5;
  int n0 = (bi % nbx) * 32, k0 = (bi / nbx) * 32;
  int tx = tid & 31, ty = tid >> 5;
#pragma unroll
  for (int i = 0; i < 32; i += 8)
    tile[ty + i][tx] = in[(size_t)(k0 + ty + i) * N + n0 + tx];
  __syncthreads();
#pragma unroll
  for (int i = 0; i < 32; i += 8)
    out[(size_t)(n0 + ty + i) * K + k0 + tx] = f2bf(tile[tx][ty + i]);
}

// ---------------- merged QKV GEMM: C = Xb @ W^T (2-phase double-buffered, 256 thr) ----------------
// blocks [0,512): Q (N=2048) -> Qb[b,h,s,hd] * QSCALE
// blocks [512,768): KV (N=1024) -> Kb[b,g,s,hd] (n<512) / VT (n>=512)
// XCD-chunked block swizzle (T1): under round-robin dispatch XCD = bid%8, so
// chunk x = bid&7 owns a square 8bm x 8bn (Q) / 8bm x 4bn (KV) tile region.
// Default mapping put every A-panel on all 8 XCDs (FETCH 137 MB, ~5x ideal);
// chunking cuts A re-fetch to 2 XCDs per panel.
// NOTE (R8 lesson): this single-barrier 2-phase loop IS the T3-minimum. Adding
// counted-vmcnt + extra barriers serialized the waves (MfmaUtil 16%) — reverted.
__global__ __launch_bounds__(256) void gemm_qkv(const u16* __restrict__ A,
                                                const u16* __restrict__ Wqt,
                                                const u16* __restrict__ Wkvt,
                                                u16* __restrict__ Qb,
                                                u16* __restrict__ KVb) {
  __shared__ u16 la0[4096], la1[4096], lb0[4096], lb1[4096];
  int tid = threadIdx.x, bx = blockIdx.x;
  int mode, bm, bn;
  const u16* Bt;
  if (bx < 512) {
    mode = 0; Bt = Wqt;
    int x = bx & 7, i = bx >> 3;         // chunk = XCD, 64 blocks each
    bm = (x >> 1) * 8 + (i >> 3);        // 32 bm total
    bn = (x & 1) * 8 + (i & 7);          // 16 bn total
  } else {
    mode = 1; Bt = Wkvt;
    int b2 = bx - 512;
    int x = b2 & 7, i = b2 >> 3;         // chunk = XCD, 32 blocks each
    bm = (x >> 1) * 8 + (i >> 2);        // 32 bm total
    bn = (x & 1) * 4 + (i & 3);          // 8 bn total
  }
  const int K = 2048;
  int w = tid >> 6, lane = tid & 63, qd = lane >> 4, ln = lane & 15;
  int wm = w >> 1, wn = w & 1;
  f32x4 acc[4][4];
#pragma unroll
  for (int i = 0; i < 4; ++i)
#pragma unroll
    for (int j = 0; j < 4; ++j) acc[i][j] = {0.f, 0.f, 0.f, 0.f};

  const u16* Ab = A + (size_t)bm * 128 * K;
  const u16* Bb = Bt + (size_t)bn * 128 * K;
  int row0 = tid >> 2, c0 = tid & 3;
  int g0 = c0 ^ (row0 & 3) ^ ((row0 >> 2) & 3);
  int s1 = tid + 256, row1 = s1 >> 2, c1 = s1 & 3;
  int g1 = c1 ^ (row1 & 3) ^ ((row1 >> 2) & 3);
  int pat = (ln & 3) ^ ((ln >> 2) & 3);
  int goff = (qd ^ pat) * 8;
  const u16* pa0 = Ab + (size_t)row0 * K + g0 * 8;
  const u16* pa1 = Ab + (size_t)row1 * K + g1 * 8;
  const u16* pb0 = Bb + (size_t)row0 * K + g0 * 8;
  const u16* pb1 = Bb + (size_t)row1 * K + g1 * 8;

#define QKV_STAGE(LA, LB, OFS)                      \
  async16(pa0 + (OFS), &LA[tid * 8]);               \
  async16(pa1 + (OFS), &LA[2048 + tid * 8]);        \
  async16(pb0 + (OFS), &LB[tid * 8]);               \
  async16(pb1 + (OFS), &LB[2048 + tid * 8]);

#define QKV_COMPUTE(LA, LB)                                                        \
  {                                                                                \
    short8 af[4], bf[4];                                                           \
    _Pragma("unroll") for (int i = 0; i < 4; ++i)                                  \
        af[i] = *(const short8*)&LA[(wm * 64 + i * 16 + ln) * 32 + goff];          \
    _Pragma("unroll") for (int j = 0; j < 4; ++j)                                  \
        bf[j] = *(const short8*)&LB[(wn * 64 + j * 16 + ln) * 32 + goff];          \
    __builtin_amdgcn_s_setprio(1);                                                 \
    _Pragma("unroll") for (int i = 0; i < 4; ++i)                                  \
      _Pragma("unroll") for (int j = 0; j < 4; ++j)                                \
        acc[i][j] =                                                                \
            __builtin_amdgcn_mfma_f32_16x16x32_bf16(af[i], bf[j], acc[i][j], 0, 0, 0); \
    __builtin_amdgcn_s_setprio(0);                                                 \
  }

  // prologue: stage kt=0 into buf0
  QKV_STAGE(la0, lb0, 0);
  __syncthreads();

  for (int kt = 0; kt < K; kt += 64) {
    // step A: prefetch kt+32 -> buf1, compute buf0
    QKV_STAGE(la1, lb1, kt + 32);
    QKV_COMPUTE(la0, lb0);
    __syncthreads();
    // step B: prefetch kt+64 -> buf0, compute buf1
    if (kt + 64 < K) { QKV_STAGE(la0, lb0, kt + 64); }
    QKV_COMPUTE(la1, lb1);
    __syncthreads();
  }
#undef QKV_STAGE
#undef QKV_COMPUTE

#pragma unroll
  for (int i = 0; i < 4; ++i)
#pragma unroll
    for (int r = 0; r < 4; ++r) {
      int m = bm * 128 + wm * 64 + i * 16 + qd * 4 + r;
      int b = m >> 11, s = m & 2047;
#pragma unroll
      for (int j = 0; j < 4; ++j) {
        int n = bn * 128 + wn * 64 + j * 16 + ln;
        float v = acc[i][j][r];
        int hh = n >> 6, hd = n & 63;
        if (mode == 0) {
          Qb[(((size_t)(b * NH + hh)) * S_LEN + s) * 64 + hd] = f2bf(v * QSCALE);
        } else {
          if (hh < 8)
            KVb[(((size_t)(b * NKV + hh)) * S_LEN + s) * 64 + hd] = f2bf(v);
          else
            KVb[2097152 + (((size_t)(b * NKV + (hh - 8))) * 64 + hd) * S_LEN + s] = f2bf(v);
        }
      }
    }
}

// ---------------- out GEMM: out[M,N] f32 = Ab @ Wot^T (2-phase double-buffered, 256 thr) ----------------
// Same XCD-chunked swizzle: chunk x = bid&7 owns an 8bm x 8bn region.
__global__ __launch_bounds__(256) void gemm_out(const u16* __restrict__ A,
                                                const u16* __restrict__ Bt,
                                                float* __restrict__ outp) {
  __shared__ u16 la0[4096], la1[4096], lb0[4096], lb1[4096];
  const int K = 2048, N = 2048;
  int tid = threadIdx.x;
  int x = blockIdx.x & 7, ii = blockIdx.x >> 3;
  int bm = (x >> 1) * 8 + (ii >> 3);
  int bn = (x & 1) * 8 + (ii & 7);
  int w = tid >> 6, lane = tid & 63, qd = lane >> 4, ln = lane & 15;
  int wm = w >> 1, wn = w & 1;
  f32x4 acc[4][4];
#pragma unroll
  for (int i = 0; i < 4; ++i)
#pragma unroll
    for (int j = 0; j < 4; ++j) acc[i][j] = {0.f, 0.f, 0.f, 0.f};

  const u16* Ab = A + (size_t)bm * 128 * K;
  const u16* Bb = Bt + (size_t)bn * 128 * K;
  int row0 = tid >> 2, c0 = tid & 3;
  int g0 = c0 ^ (row0 & 3) ^ ((row0 >> 2) & 3);
  int s1 = tid + 256, row1 = s1 >> 2, c1 = s1 & 3;
  int g1 = c1 ^ (row1 & 3) ^ ((row1 >> 2) & 3);
  int pat = (ln & 3) ^ ((ln >> 2) & 3);
  int goff = (qd ^ pat) * 8;
  const u16* pa0 = Ab + (size_t)row0 * K + g0 * 8;
  const u16* pa1 = Ab + (size_t)row1 * K + g1 * 8;
  const u16* pb0 = Bb + (size_t)row0 * K + g0 * 8;
  const u16* pb1 = Bb + (size_t)row1 * K + g1 * 8;

#define OUT_STAGE(LA, LB, OFS)                      \
  async16(pa0 + (OFS), &LA[tid * 8]);               \
  async16(pa1 + (OFS), &LA[2048 + tid * 8]);        \
  async16(pb0 + (OFS), &LB[tid * 8]);               \
  async16(pb1 + (OFS), &LB[2048 + tid * 8]);

#define OUT_COMPUTE(LA, LB)                                                        \
  {                                                                                \
    short8 af[4], bf[4];                                                           \
    _Pragma("unroll") for (int i = 0; i < 4; ++i)                                  \
        af[i] = *(const short8*)&LA[(wm * 64 + i * 16 + ln) * 32 + goff];          \
    _Pragma("unroll") for (int j = 0; j < 4; ++j)                                  \
        bf[j] = *(const short8*)&LB[(wn * 64 + j * 16 + ln) * 32 + goff];          \
    __builtin_amdgcn_s_setprio(1);                                                 \
    _Pragma("unroll") for (int i = 0; i < 4; ++i)                                  \
      _Pragma("unroll") for (int j = 0; j < 4; ++j)                                \
        acc[i][j] =                                                                \
            __builtin_amdgcn_mfma_f32_16x16x32_bf16(af[i], bf[j], acc[i][j], 0, 0, 0); \
    __builtin_amdgcn_s_setprio(0);                                                 \
  }

  // prologue: stage kt=0 into buf0
  OUT_STAGE(la0, lb0, 0);
  __syncthreads();

  for (int kt = 0; kt < K; kt += 64) {
    // step A: prefetch kt+32 -> buf1, compute buf0
    OUT_STAGE(la1, lb1, kt + 32);
    OUT_COMPUTE(la0, lb0);
    __syncthreads();
    // step B: prefetch kt+64 -> buf0, compute buf1
    if (kt + 64 < K) { OUT_STAGE(la0, lb0, kt + 64); }
    OUT_COMPUTE(la1, lb1);
    __syncthreads();
  }
#undef OUT_STAGE
#undef OUT_COMPUTE

#pragma unroll
  for (int i = 0; i < 4; ++i)
#pragma unroll
    for (int r = 0; r < 4; ++r) {
      int m = bm * 128 + wm * 64 + i * 16 + qd * 4 + r;
#pragma unroll
      for (int j = 0; j < 4; ++j) {
        int n = bn * 128 + wn * 64 + j * 16 + ln;
        outp[(size_t)m * N + n] = acc[i][j][r];
      }
    }
}

// ---------------- flash attention: 64 q per wave (K/V fragment reuse x2) ----------------
// Verified 92 us (R7/R9). XCD swizzle (qt=bid>>6, bh=bid&63) cut FETCH 41->28 MB;
// dur unchanged -> issue-bound (MFMA 31% + VALU 48% + trans ~ saturated). Parked.
__global__ __launch_bounds__(256, 2) void attn_kernel(const u16* __restrict__ Q,
                                                      const u16* __restrict__ K,
                                                      const u16* __restrict__ VT,
                                                      u16* __restrict__ Ao) {
  __shared__ u16 sh[16384];  // [0,4096) K buf0 | [4096,8192) K buf1 | [8192,12288) V buf0 | [12288,16384) V buf1
  int tid = threadIdx.x;
  int w = tid >> 6, lane = tid & 63;
  int l31 = lane & 31, l5 = lane >> 5;
  int qt = blockIdx.x >> 6, bh = blockIdx.x & 63;  // XCD swizzle: bh%8 pins the XCD
  int b = bh >> 5, h = bh & 31, g = h >> 2;
  const u16* gQ = Q + ((size_t)bh * S_LEN + qt * 256) * 64;
  const u16* gK = K + (size_t)(b * NKV + g) * S_LEN * 64;
  const u16* gV = VT + (size_t)(b * NKV + g) * 64 * S_LEN;

  int p7 = l31 & 7;

  // staging index precompute (shared by K and V chunk staging)
  int s0 = tid, r0 = s0 >> 3, c0 = s0 & 7, gg0 = c0 ^ (r0 & 7);
  int s1 = tid + 256, r1 = s1 >> 3, c1 = s1 & 7, gg1 = c1 ^ (r1 & 7);

  // ---- stage Q tile [256 q][8 granules] swizzled into the whole 32KB buffer ----
#pragma unroll
  for (int k = 0; k < 8; ++k) {
    int s = tid + k * 256;
    int q = s >> 3, c = s & 7, gg = c ^ (q & 7);
    async16(gQ + (size_t)q * 64 + gg * 8, &sh[s * 8]);
  }
  __syncthreads();
  // qf[qg][ks]: B-operand, lane holds Q[q = w*64 + qg*32 + l31][d = ks*16 + l5*8 + 0..7]
  short8 qf[2][4];
#pragma unroll
  for (int qg = 0; qg < 2; ++qg) {
    int qrow = w * 64 + qg * 32 + l31;
#pragma unroll
    for (int ks = 0; ks < 4; ++ks)
      qf[qg][ks] = *(const short8*)&sh[qrow * 64 + ((ks * 2 + l5) ^ p7) * 8];
  }
  __syncthreads();  // all waves done reading Q before sh is restaged with K/V

  // ---- stage chunk 0 ----
  async16(gK + (size_t)r0 * 64 + gg0 * 8, &sh[s0 * 8]);
  async16(gK + (size_t)r1 * 64 + gg1 * 8, &sh[s1 * 8]);
  async16(gV + (size_t)r0 * S_LEN + gg0 * 8, &sh[8192 + s0 * 8]);
  async16(gV + (size_t)r1 * S_LEN + gg1 * 8, &sh[8192 + s1 * 8]);
  __syncthreads();  // chunk 0 resident before first compute (drains vmcnt)

  const f32x16 psh16 = {-PSHIFT, -PSHIFT, -PSHIFT, -PSHIFT, -PSHIFT, -PSHIFT,
                        -PSHIFT, -PSHIFT, -PSHIFT, -PSHIFT, -PSHIFT, -PSHIFT,
                        -PSHIFT, -PSHIFT, -PSHIFT, -PSHIFT};
  f32x16 accA0, accA1, accB0, accB1;  // acc{qg}{hb}: named, no runtime indexing
#pragma unroll
  for (int t = 0; t < 16; ++t) { accA0[t] = 0.f; accA1[t] = 0.f; accB0[t] = 0.f; accB1[t] = 0.f; }
  float liA = 0.f, liB = 0.f;

  // p = exp2(sc); pack to bf16 pairs; permlane32_swap re-layouts to PV B-fragments.
#define SOFTMAX32(SC, LI, PF0, PF1)                                              \
  short8 PF0, PF1;                                                               \
  {                                                                              \
    float p[16];                                                                 \
    _Pragma("unroll") for (int t = 0; t < 16; ++t) p[t] = fexp2(SC[t]);          \
    _Pragma("unroll") for (int t = 0; t < 16; t += 4)                            \
        LI += (p[t] + p[t + 1]) + (p[t + 2] + p[t + 3]);                         \
    unsigned W[8];                                                               \
    _Pragma("unroll") for (int t = 0; t < 8; ++t) W[t] = pk2bf(p[2 * t], p[2 * t + 1]); \
    auto ra = __builtin_amdgcn_permlane32_swap((int)W[0], (int)W[2], false, false); \
    auto rb = __builtin_amdgcn_permlane32_swap((int)W[1], (int)W[3], false, false); \
    auto rc = __builtin_amdgcn_permlane32_swap((int)W[4], (int)W[6], false, false); \
    auto rd = __builtin_amdgcn_permlane32_swap((int)W[5], (int)W[7], false, false); \
    PF0 = mk_pf((unsigned)ra[0], (unsigned)rb[0], (unsigned)ra[1], (unsigned)rb[1]); \
    PF1 = mk_pf((unsigned)rc[0], (unsigned)rd[0], (unsigned)rc[1], (unsigned)rd[1]); \
  }

  for (int c = 0; c < 32; ++c) {
    int cur = c & 1;
    // ---- prefetch chunk c+1 into the other buffer (overlaps with compute) ----
    if (c < 31) {
      int nb = cur ^ 1, cn = c + 1;
      async16(gK + (size_t)(cn * 64 + r0) * 64 + gg0 * 8, &sh[nb * 4096 + s0 * 8]);
      async16(gK + (size_t)(cn * 64 + r1) * 64 + gg1 * 8, &sh[nb * 4096 + s1 * 8]);
      async16(gV + (size_t)r0 * S_LEN + cn * 64 + gg0 * 8, &sh[8192 + nb * 4096 + s0 * 8]);
      async16(gV + (size_t)r1 * S_LEN + cn * 64 + gg1 * 8, &sh[8192 + nb * 4096 + s1 * 8]);
    }
    const u16* kb = &sh[cur * 4096];
    const u16* vb = &sh[8192 + cur * 4096];

#pragma unroll
    for (int kblk = 0; kblk < 2; ++kblk) {
      // ---- scores: one K-frag read feeds BOTH q-groups' 32x32 MFMAs ----
      f32x16 scA = psh16, scB = psh16;
      __builtin_amdgcn_s_setprio(1);
#pragma unroll
      for (int ks = 0; ks < 4; ++ks) {
        short8 kf = *(const short8*)&kb[(kblk * 32 + l31) * 64 + ((ks * 2 + l5) ^ p7) * 8];
        scA = __builtin_amdgcn_mfma_f32_32x32x16_bf16(kf, qf[0][ks], scA, 0, 0, 0);
        scB = __builtin_amdgcn_mfma_f32_32x32x16_bf16(kf, qf[1][ks], scB, 0, 0, 0);
      }
      __builtin_amdgcn_s_setprio(0);

      // ---- in-register softmax for both q-groups ----
      SOFTMAX32(scA, liA, pfA0, pfA1)
      SOFTMAX32(scB, liB, pfB0, pfB1)

      // ---- PV: each V-frag read feeds BOTH q-groups ----
      __builtin_amdgcn_s_setprio(1);
#pragma unroll
      for (int hb = 0; hb < 2; ++hb) {
        short8 vf = *(const short8*)&vb[(hb * 32 + l31) * 64 + ((kblk * 4 + l5) ^ p7) * 8];
        if (hb == 0) {
          accA0 = __builtin_amdgcn_mfma_f32_32x32x16_bf16(vf, pfA0, accA0, 0, 0, 0);
          accB0 = __builtin_amdgcn_mfma_f32_32x32x16_bf16(vf, pfB0, accB0, 0, 0, 0);
        } else {
          accA1 = __builtin_amdgcn_mfma_f32_32x32x16_bf16(vf, pfA0, accA1, 0, 0, 0);
          accB1 = __builtin_amdgcn_mfma_f32_32x32x16_bf16(vf, pfB0, accB1, 0, 0, 0);
        }
      }
#pragma unroll
      for (int hb = 0; hb < 2; ++hb) {
        short8 vf = *(const short8*)&vb[(hb * 32 + l31) * 64 + ((kblk * 4 + 2 + l5) ^ p7) * 8];
        if (hb == 0) {
          accA0 = __builtin_amdgcn_mfma_f32_32x32x16_bf16(vf, pfA1, accA0, 0, 0, 0);
          accB0 = __builtin_amdgcn_mfma_f32_32x32x16_bf16(vf, pfB1, accB0, 0, 0, 0);
        } else {
          accA1 = __builtin_amdgcn_mfma_f32_32x32x16_bf16(vf, pfA1, accA1, 0, 0, 0);
          accB1 = __builtin_amdgcn_mfma_f32_32x32x16_bf16(vf, pfB1, accB1, 0, 0, 0);
        }
      }
      __builtin_amdgcn_s_setprio(0);
    }
    __syncthreads();  // drains prefetch + protects buffers for c+2 staging
  }
#undef SOFTMAX32

  // ---- epilogue: reduce l across lane-halves once per q-group, then store ----
  {
    float l = liA + __shfl_xor(liA, 32);
    float inv = 1.f / l;
    int q = qt * 256 + w * 64 + l31;
    size_t base = ((size_t)b * S_LEN + q) * 2048 + h * 64;
#pragma unroll
    for (int rq = 0; rq < 4; ++rq) {
      u16x4 o0, o1;
#pragma unroll
      for (int rr = 0; rr < 4; ++rr) {
        o0[rr] = f2bf(accA0[rq * 4 + rr] * inv);
        o1[rr] = f2bf(accA1[rq * 4 + rr] * inv);
      }
      *(u16x4*)&Ao[base + rq * 8 + l5 * 4] = o0;
      *(u16x4*)&Ao[base + 32 + rq * 8 + l5 * 4] = o1;
    }
  }
  {
    float l = liB + __shfl_xor(liB, 32);
    float inv = 1.f / l;
    int q = qt * 256 + w * 64 + 32 + l31;
    size_t base = ((size_t)b * S_LEN + q) * 2048 + h * 64;
#pragma unroll
    for (int rq = 0; rq < 4; ++rq) {
      u16x4 o0, o1;
#pragma unroll
      for (int rr = 0; rr < 4; ++rr) {
        o0[rr] = f2bf(accB0[rq * 4 + rr] * inv);
        o1[rr] = f2bf(accB1[rq * 4 + rr] * inv);
      }
      *(u16x4*)&Ao[base + rq * 8 + l5 * 4] = o0;
      *(u16x4*)&Ao[base + 32 + rq * 8 + l5 * 4] = o1;
    }
  }
}

extern "C" void kernel_launch(void* const* d_in, const int* in_sizes, int n_in,
                              void* d_out, int out_size, void* d_ws, size_t ws_size,
                              hipStream_t stream) {
  const float* X  = (const float*)d_in[0];
  const float* Wq = (const float*)d_in[1];
  const float* Wk = (const float*)d_in[2];
  const float* Wv = (const float*)d_in[3];
  const float* Wo = (const float*)d_in[4];
  char* ws = (char*)d_ws;
  u16* Xb  = (u16*)(ws);                  // 16 MB  [4096][2048]
  u16* Wqt = (u16*)(ws + 16777216);       //  8 MB  [2048][2048]
  u16* Wkt = (u16*)(ws + 25165824);       //  2 MB  [512][2048]   (K rows)
  u16* Wvt = (u16*)(ws + 27262976);       //  2 MB  [512][2048]   (V rows, contiguous after K)
  u16* Wot = (u16*)(ws + 29360128);       //  8 MB  [2048][2048]
  u16* Qb  = (u16*)(ws + 37748736);       // 16 MB  [B,H,S,64]
  u16* Kb  = (u16*)(ws + 54525952);       //  4 MB  [B,KVH,S,64]; VT at Kb+2097152 u16
  u16* VTb = (u16*)(ws + 58720256);       //  4 MB  [B,KVH,64,S]
  u16* Ab  = (u16*)(ws + 62914560);       // 16 MB  [4096][2048]
  float* out = (float*)d_out;

  prep_kernel<<<18432, 256, 0, stream>>>(X, Wq, Wk, Wv, Wo, Xb, Wqt, Wkt, Wvt, Wot);
  gemm_qkv<<<768, 256, 0, stream>>>(Xb, Wqt, Wkt, Qb, Kb);
  attn_kernel<<<512, 256, 0, stream>>>(Qb, Kb, VTb, Ab);
  gemm_out<<<512, 256, 0, stream>>>(Ab, Wot, out);
}

// Round 11
// 302.392 us; speedup vs baseline: 1.0008x; 1.0008x over previous
//
#include <hip/hip_runtime.h>
#include <hip/hip_bf16.h>

typedef unsigned short u16;
typedef __attribute__((ext_vector_type(8))) short short8;
typedef __attribute__((ext_vector_type(4))) float f32x4;
typedef __attribute__((ext_vector_type(16))) float f32x16;
typedef __attribute__((ext_vector_type(4))) unsigned short u16x4;
typedef __attribute__((ext_vector_type(4))) int int4v;

#define S_LEN 2048
#define NH 32
#define NKV 8
// HD = 64, G = 4, D = 2048, M = B*S = 4096
// Q is pre-scaled by 0.125 * log2(e) so softmax runs in exp2 space.
#define QSCALE 0.18033688011112042f
// Fixed softmax shift (softmax is shift-invariant; |scores| << 14 always here)
#define PSHIFT 14.0f

__device__ __forceinline__ float fexp2(float x) { return __builtin_amdgcn_exp2f(x); }

__device__ __forceinline__ u16 f2bf(float f) {
  unsigned int u = __builtin_bit_cast(unsigned int, f);
  u += 0x7fffu + ((u >> 16) & 1u);
  return (u16)(u >> 16);
}

__device__ __forceinline__ unsigned int pk2bf(float a, float b) {
  float2 t; t.x = a; t.y = b;
  __hip_bfloat162 h = __float22bfloat162_rn(t);
  unsigned int r;
  __builtin_memcpy(&r, &h, 4);
  return r;
}

__device__ __forceinline__ void async16(const void* g, void* l) {
  __builtin_amdgcn_global_load_lds(
      (__attribute__((address_space(1))) void*)g,
      (__attribute__((address_space(3))) void*)l, 16, 0, 0);
}

__device__ __forceinline__ short8 mk_pf(unsigned a, unsigned b, unsigned c, unsigned d) {
  int4v t; t.x = (int)a; t.y = (int)b; t.z = (int)c; t.w = (int)d;
  return __builtin_bit_cast(short8, t);
}

// -------- prep: X cast (blocks 0..8191) + 4 weight transposes (8192..18431) --------
__global__ __launch_bounds__(256) void prep_kernel(const float* __restrict__ X,
                                                   const float* __restrict__ Wq,
                                                   const float* __restrict__ Wk,
                                                   const float* __restrict__ Wv,
                                                   const float* __restrict__ Wo,
                                                   u16* __restrict__ Xb,
                                                   u16* __restrict__ Wqt,
                                                   u16* __restrict__ Wkt,
                                                   u16* __restrict__ Wvt,
                                                   u16* __restrict__ Wot) {
  __shared__ float tile[32][33];
  int bx = blockIdx.x, tid = threadIdx.x;
  if (bx < 8192) {
    int idx = bx * 256 + tid;
    float4 v = ((const float4*)X)[idx];
    u16x4 o;
    o.x = f2bf(v.x); o.y = f2bf(v.y); o.z = f2bf(v.z); o.w = f2bf(v.w);
    *(u16x4*)&Xb[(size_t)idx * 4] = o;
    return;
  }
  const float* in; u16* out; int N, bi;
  if (bx < 12288)      { bi = bx - 8192;  in = Wq; out = Wqt; N = 2048; }
  else if (bx < 13312) { bi = bx - 12288; in = Wk; out = Wkt; N = 512; }
  else if (bx < 14336) { bi = bx - 13312; in = Wv; out = Wvt; N = 512; }
  else                 { bi = bx - 14336; in = Wo; out = Wot; N = 2048; }
  const int K = 2048;
  int nbx = N >> 5;
  int n0 = (bi % nbx) * 32, k0 = (bi / nbx) * 32;
  int tx = tid & 31, ty = tid >> 5;
#pragma unroll
  for (int i = 0; i < 32; i += 8)
    tile[ty + i][tx] = in[(size_t)(k0 + ty + i) * N + n0 + tx];
  __syncthreads();
#pragma unroll
  for (int i = 0; i < 32; i += 8)
    out[(size_t)(n0 + ty + i) * K + k0 + tx] = f2bf(tile[tx][ty + i]);
}

// ---------------- merged QKV GEMM: C = Xb @ W^T (2-phase double-buffered, 256 thr) ----------------
// blocks [0,512): Q (N=2048) -> Qb[b,h,s,hd] * QSCALE
// blocks [512,768): KV (N=1024) -> Kb[b,g,s,hd] (n<512) / VT (n>=512)
// XCD-chunked block swizzle (T1) kept from R10 (fetch 137->~70 MB, time-neutral
// but harmless). R8 lesson: this single-barrier 2-phase loop IS the T3-minimum;
// counted-vmcnt grafting serialized waves (MfmaUtil 16%). V^T epilogue stores
// vectorized u16x4 over r (4 consecutive s) — 4x fewer scattered stores.
__global__ __launch_bounds__(256) void gemm_qkv(const u16* __restrict__ A,
                                                const u16* __restrict__ Wqt,
                                                const u16* __restrict__ Wkvt,
                                                u16* __restrict__ Qb,
                                                u16* __restrict__ KVb) {
  __shared__ u16 la0[4096], la1[4096], lb0[4096], lb1[4096];
  int tid = threadIdx.x, bx = blockIdx.x;
  int mode, bm, bn;
  const u16* Bt;
  if (bx < 512) {
    mode = 0; Bt = Wqt;
    int x = bx & 7, i = bx >> 3;         // chunk = XCD, 64 blocks each
    bm = (x >> 1) * 8 + (i >> 3);        // 32 bm total
    bn = (x & 1) * 8 + (i & 7);          // 16 bn total
  } else {
    mode = 1; Bt = Wkvt;
    int b2 = bx - 512;
    int x = b2 & 7, i = b2 >> 3;         // chunk = XCD, 32 blocks each
    bm = (x >> 1) * 8 + (i >> 2);        // 32 bm total
    bn = (x & 1) * 4 + (i & 3);          // 8 bn total
  }
  const int K = 2048;
  int w = tid >> 6, lane = tid & 63, qd = lane >> 4, ln = lane & 15;
  int wm = w >> 1, wn = w & 1;
  f32x4 acc[4][4];
#pragma unroll
  for (int i = 0; i < 4; ++i)
#pragma unroll
    for (int j = 0; j < 4; ++j) acc[i][j] = {0.f, 0.f, 0.f, 0.f};

  const u16* Ab = A + (size_t)bm * 128 * K;
  const u16* Bb = Bt + (size_t)bn * 128 * K;
  int row0 = tid >> 2, c0 = tid & 3;
  int g0 = c0 ^ (row0 & 3) ^ ((row0 >> 2) & 3);
  int s1 = tid + 256, row1 = s1 >> 2, c1 = s1 & 3;
  int g1 = c1 ^ (row1 & 3) ^ ((row1 >> 2) & 3);
  int pat = (ln & 3) ^ ((ln >> 2) & 3);
  int goff = (qd ^ pat) * 8;
  const u16* pa0 = Ab + (size_t)row0 * K + g0 * 8;
  const u16* pa1 = Ab + (size_t)row1 * K + g1 * 8;
  const u16* pb0 = Bb + (size_t)row0 * K + g0 * 8;
  const u16* pb1 = Bb + (size_t)row1 * K + g1 * 8;

#define QKV_STAGE(LA, LB, OFS)                      \
  async16(pa0 + (OFS), &LA[tid * 8]);               \
  async16(pa1 + (OFS), &LA[2048 + tid * 8]);        \
  async16(pb0 + (OFS), &LB[tid * 8]);               \
  async16(pb1 + (OFS), &LB[2048 + tid * 8]);

#define QKV_COMPUTE(LA, LB)                                                        \
  {                                                                                \
    short8 af[4], bf[4];                                                           \
    _Pragma("unroll") for (int i = 0; i < 4; ++i)                                  \
        af[i] = *(const short8*)&LA[(wm * 64 + i * 16 + ln) * 32 + goff];          \
    _Pragma("unroll") for (int j = 0; j < 4; ++j)                                  \
        bf[j] = *(const short8*)&LB[(wn * 64 + j * 16 + ln) * 32 + goff];          \
    __builtin_amdgcn_s_setprio(1);                                                 \
    _Pragma("unroll") for (int i = 0; i < 4; ++i)                                  \
      _Pragma("unroll") for (int j = 0; j < 4; ++j)                                \
        acc[i][j] =                                                                \
            __builtin_amdgcn_mfma_f32_16x16x32_bf16(af[i], bf[j], acc[i][j], 0, 0, 0); \
    __builtin_amdgcn_s_setprio(0);                                                 \
  }

  // prologue: stage kt=0 into buf0
  QKV_STAGE(la0, lb0, 0);
  __syncthreads();

  for (int kt = 0; kt < K; kt += 64) {
    // step A: prefetch kt+32 -> buf1, compute buf0
    QKV_STAGE(la1, lb1, kt + 32);
    QKV_COMPUTE(la0, lb0);
    __syncthreads();
    // step B: prefetch kt+64 -> buf0, compute buf1
    if (kt + 64 < K) { QKV_STAGE(la0, lb0, kt + 64); }
    QKV_COMPUTE(la1, lb1);
    __syncthreads();
  }
#undef QKV_STAGE
#undef QKV_COMPUTE

#pragma unroll
  for (int i = 0; i < 4; ++i) {
    int m0 = bm * 128 + wm * 64 + i * 16 + qd * 4;
    int b = m0 >> 11, s0 = m0 & 2047;   // s0 % 4 == 0; r spans s0..s0+3
#pragma unroll
    for (int j = 0; j < 4; ++j) {
      int n = bn * 128 + wn * 64 + j * 16 + ln;
      int hh = n >> 6, hd = n & 63;
      if (mode == 0) {
#pragma unroll
        for (int r = 0; r < 4; ++r)
          Qb[(((size_t)(b * NH + hh)) * S_LEN + s0 + r) * 64 + hd] =
              f2bf(acc[i][j][r] * QSCALE);
      } else if (hh < 8) {
#pragma unroll
        for (int r = 0; r < 4; ++r)
          KVb[(((size_t)(b * NKV + hh)) * S_LEN + s0 + r) * 64 + hd] =
              f2bf(acc[i][j][r]);
      } else {
        u16x4 o;
#pragma unroll
        for (int r = 0; r < 4; ++r) o[r] = f2bf(acc[i][j][r]);
        *(u16x4*)&KVb[2097152 + (((size_t)(b * NKV + (hh - 8))) * 64 + hd) * S_LEN + s0] = o;
      }
    }
  }
}

// ---------------- out GEMM: out[M,N] f32 = Ab @ Wot^T (2-phase double-buffered, 256 thr) ----------------
// Same XCD-chunked swizzle: chunk x = bid&7 owns an 8bm x 8bn region.
__global__ __launch_bounds__(256) void gemm_out(const u16* __restrict__ A,
                                                const u16* __restrict__ Bt,
                                                float* __restrict__ outp) {
  __shared__ u16 la0[4096], la1[4096], lb0[4096], lb1[4096];
  const int K = 2048, N = 2048;
  int tid = threadIdx.x;
  int x = blockIdx.x & 7, ii = blockIdx.x >> 3;
  int bm = (x >> 1) * 8 + (ii >> 3);
  int bn = (x & 1) * 8 + (ii & 7);
  int w = tid >> 6, lane = tid & 63, qd = lane >> 4, ln = lane & 15;
  int wm = w >> 1, wn = w & 1;
  f32x4 acc[4][4];
#pragma unroll
  for (int i = 0; i < 4; ++i)
#pragma unroll
    for (int j = 0; j < 4; ++j) acc[i][j] = {0.f, 0.f, 0.f, 0.f};

  const u16* Ab = A + (size_t)bm * 128 * K;
  const u16* Bb = Bt + (size_t)bn * 128 * K;
  int row0 = tid >> 2, c0 = tid & 3;
  int g0 = c0 ^ (row0 & 3) ^ ((row0 >> 2) & 3);
  int s1 = tid + 256, row1 = s1 >> 2, c1 = s1 & 3;
  int g1 = c1 ^ (row1 & 3) ^ ((row1 >> 2) & 3);
  int pat = (ln & 3) ^ ((ln >> 2) & 3);
  int goff = (qd ^ pat) * 8;
  const u16* pa0 = Ab + (size_t)row0 * K + g0 * 8;
  const u16* pa1 = Ab + (size_t)row1 * K + g1 * 8;
  const u16* pb0 = Bb + (size_t)row0 * K + g0 * 8;
  const u16* pb1 = Bb + (size_t)row1 * K + g1 * 8;

#define OUT_STAGE(LA, LB, OFS)                      \
  async16(pa0 + (OFS), &LA[tid * 8]);               \
  async16(pa1 + (OFS), &LA[2048 + tid * 8]);        \
  async16(pb0 + (OFS), &LB[tid * 8]);               \
  async16(pb1 + (OFS), &LB[2048 + tid * 8]);

#define OUT_COMPUTE(LA, LB)                                                        \
  {                                                                                \
    short8 af[4], bf[4];                                                           \
    _Pragma("unroll") for (int i = 0; i < 4; ++i)                                  \
        af[i] = *(const short8*)&LA[(wm * 64 + i * 16 + ln) * 32 + goff];          \
    _Pragma("unroll") for (int j = 0; j < 4; ++j)                                  \
        bf[j] = *(const short8*)&LB[(wn * 64 + j * 16 + ln) * 32 + goff];          \
    __builtin_amdgcn_s_setprio(1);                                                 \
    _Pragma("unroll") for (int i = 0; i < 4; ++i)                                  \
      _Pragma("unroll") for (int j = 0; j < 4; ++j)                                \
        acc[i][j] =                                                                \
            __builtin_amdgcn_mfma_f32_16x16x32_bf16(af[i], bf[j], acc[i][j], 0, 0, 0); \
    __builtin_amdgcn_s_setprio(0);                                                 \
  }

  // prologue: stage kt=0 into buf0
  OUT_STAGE(la0, lb0, 0);
  __syncthreads();

  for (int kt = 0; kt < K; kt += 64) {
    // step A: prefetch kt+32 -> buf1, compute buf0
    OUT_STAGE(la1, lb1, kt + 32);
    OUT_COMPUTE(la0, lb0);
    __syncthreads();
    // step B: prefetch kt+64 -> buf0, compute buf1
    if (kt + 64 < K) { OUT_STAGE(la0, lb0, kt + 64); }
    OUT_COMPUTE(la1, lb1);
    __syncthreads();
  }
#undef OUT_STAGE
#undef OUT_COMPUTE

#pragma unroll
  for (int i = 0; i < 4; ++i)
#pragma unroll
    for (int r = 0; r < 4; ++r) {
      int m = bm * 128 + wm * 64 + i * 16 + qd * 4 + r;
#pragma unroll
      for (int j = 0; j < 4; ++j) {
        int n = bn * 128 + wn * 64 + j * 16 + ln;
        outp[(size_t)m * N + n] = acc[i][j][r];
      }
    }
}

// ---------------- flash attention: 64 q per wave (K/V fragment reuse x2) ----------------
// 92 us verified (R7/R9/R10); XCD swizzle cut FETCH 41->28 MB (time-neutral:
// issue-bound). This round: row-sum l moved from VALU to the MFMA pipe via the
// ones-row trick — l[q] = mfma(ones, pf, lacc): with A=all-ones every D row is
// Sum_kv P[kv][q], so lacc[0] is the denominator directly (no epilogue shuffle;
// lane halves agree). Removes 48 VALU adds/chunk from the widest pipe (48%)
// onto the 31%-utilized MFMA pipe, and makes the denominator sum the same
// bf16-rounded P used by PV.
__global__ __launch_bounds__(256, 2) void attn_kernel(const u16* __restrict__ Q,
                                                      const u16* __restrict__ K,
                                                      const u16* __restrict__ VT,
                                                      u16* __restrict__ Ao) {
  __shared__ u16 sh[16384];  // [0,4096) K buf0 | [4096,8192) K buf1 | [8192,12288) V buf0 | [12288,16384) V buf1
  int tid = threadIdx.x;
  int w = tid >> 6, lane = tid & 63;
  int l31 = lane & 31, l5 = lane >> 5;
  int qt = blockIdx.x >> 6, bh = blockIdx.x & 63;  // XCD swizzle: bh%8 pins the XCD
  int b = bh >> 5, h = bh & 31, g = h >> 2;
  const u16* gQ = Q + ((size_t)bh * S_LEN + qt * 256) * 64;
  const u16* gK = K + (size_t)(b * NKV + g) * S_LEN * 64;
  const u16* gV = VT + (size_t)(b * NKV + g) * 64 * S_LEN;

  int p7 = l31 & 7;

  // staging index precompute (shared by K and V chunk staging)
  int s0 = tid, r0 = s0 >> 3, c0 = s0 & 7, gg0 = c0 ^ (r0 & 7);
  int s1 = tid + 256, r1 = s1 >> 3, c1 = s1 & 7, gg1 = c1 ^ (r1 & 7);

  // ---- stage Q tile [256 q][8 granules] swizzled into the whole 32KB buffer ----
#pragma unroll
  for (int k = 0; k < 8; ++k) {
    int s = tid + k * 256;
    int q = s >> 3, c = s & 7, gg = c ^ (q & 7);
    async16(gQ + (size_t)q * 64 + gg * 8, &sh[s * 8]);
  }
  __syncthreads();
  // qf[qg][ks]: B-operand, lane holds Q[q = w*64 + qg*32 + l31][d = ks*16 + l5*8 + 0..7]
  short8 qf[2][4];
#pragma unroll
  for (int qg = 0; qg < 2; ++qg) {
    int qrow = w * 64 + qg * 32 + l31;
#pragma unroll
    for (int ks = 0; ks < 4; ++ks)
      qf[qg][ks] = *(const short8*)&sh[qrow * 64 + ((ks * 2 + l5) ^ p7) * 8];
  }
  __syncthreads();  // all waves done reading Q before sh is restaged with K/V

  // ---- stage chunk 0 ----
  async16(gK + (size_t)r0 * 64 + gg0 * 8, &sh[s0 * 8]);
  async16(gK + (size_t)r1 * 64 + gg1 * 8, &sh[s1 * 8]);
  async16(gV + (size_t)r0 * S_LEN + gg0 * 8, &sh[8192 + s0 * 8]);
  async16(gV + (size_t)r1 * S_LEN + gg1 * 8, &sh[8192 + s1 * 8]);
  __syncthreads();  // chunk 0 resident before first compute (drains vmcnt)

  const f32x16 psh16 = {-PSHIFT, -PSHIFT, -PSHIFT, -PSHIFT, -PSHIFT, -PSHIFT,
                        -PSHIFT, -PSHIFT, -PSHIFT, -PSHIFT, -PSHIFT, -PSHIFT,
                        -PSHIFT, -PSHIFT, -PSHIFT, -PSHIFT};
  f32x16 accA0, accA1, accB0, accB1;  // acc{qg}{hb}: named, no runtime indexing
  f32x16 laccA, laccB;                // row-sum accumulators (ones-row MFMA)
#pragma unroll
  for (int t = 0; t < 16; ++t) {
    accA0[t] = 0.f; accA1[t] = 0.f; accB0[t] = 0.f; accB1[t] = 0.f;
    laccA[t] = 0.f; laccB[t] = 0.f;
  }
  short8 ones8;
#pragma unroll
  for (int t = 0; t < 8; ++t) ones8[t] = (short)0x3F80;  // bf16 1.0

  // p = exp2(sc); pack to bf16 pairs; permlane32_swap re-layouts to PV B-fragments.
#define SOFTMAX32(SC, PF0, PF1)                                                  \
  short8 PF0, PF1;                                                               \
  {                                                                              \
    float p[16];                                                                 \
    _Pragma("unroll") for (int t = 0; t < 16; ++t) p[t] = fexp2(SC[t]);          \
    unsigned W[8];                                                               \
    _Pragma("unroll") for (int t = 0; t < 8; ++t) W[t] = pk2bf(p[2 * t], p[2 * t + 1]); \
    auto ra = __builtin_amdgcn_permlane32_swap((int)W[0], (int)W[2], false, false); \
    auto rb = __builtin_amdgcn_permlane32_swap((int)W[1], (int)W[3], false, false); \
    auto rc = __builtin_amdgcn_permlane32_swap((int)W[4], (int)W[6], false, false); \
    auto rd = __builtin_amdgcn_permlane32_swap((int)W[5], (int)W[7], false, false); \
    PF0 = mk_pf((unsigned)ra[0], (unsigned)rb[0], (unsigned)ra[1], (unsigned)rb[1]); \
    PF1 = mk_pf((unsigned)rc[0], (unsigned)rd[0], (unsigned)rc[1], (unsigned)rd[1]); \
  }

  for (int c = 0; c < 32; ++c) {
    int cur = c & 1;
    // ---- prefetch chunk c+1 into the other buffer (overlaps with compute) ----
    if (c < 31) {
      int nb = cur ^ 1, cn = c + 1;
      async16(gK + (size_t)(cn * 64 + r0) * 64 + gg0 * 8, &sh[nb * 4096 + s0 * 8]);
      async16(gK + (size_t)(cn * 64 + r1) * 64 + gg1 * 8, &sh[nb * 4096 + s1 * 8]);
      async16(gV + (size_t)r0 * S_LEN + cn * 64 + gg0 * 8, &sh[8192 + nb * 4096 + s0 * 8]);
      async16(gV + (size_t)r1 * S_LEN + cn * 64 + gg1 * 8, &sh[8192 + nb * 4096 + s1 * 8]);
    }
    const u16* kb = &sh[cur * 4096];
    const u16* vb = &sh[8192 + cur * 4096];

#pragma unroll
    for (int kblk = 0; kblk < 2; ++kblk) {
      // ---- scores: one K-frag read feeds BOTH q-groups' 32x32 MFMAs ----
      f32x16 scA = psh16, scB = psh16;
      __builtin_amdgcn_s_setprio(1);
#pragma unroll
      for (int ks = 0; ks < 4; ++ks) {
        short8 kf = *(const short8*)&kb[(kblk * 32 + l31) * 64 + ((ks * 2 + l5) ^ p7) * 8];
        scA = __builtin_amdgcn_mfma_f32_32x32x16_bf16(kf, qf[0][ks], scA, 0, 0, 0);
        scB = __builtin_amdgcn_mfma_f32_32x32x16_bf16(kf, qf[1][ks], scB, 0, 0, 0);
      }
      __builtin_amdgcn_s_setprio(0);

      // ---- in-register softmax for both q-groups ----
      SOFTMAX32(scA, pfA0, pfA1)
      SOFTMAX32(scB, pfB0, pfB1)

      // ---- PV + row-sum: each V-frag read feeds BOTH q-groups; l via ones-MFMA ----
      __builtin_amdgcn_s_setprio(1);
      laccA = __builtin_amdgcn_mfma_f32_32x32x16_bf16(ones8, pfA0, laccA, 0, 0, 0);
      laccB = __builtin_amdgcn_mfma_f32_32x32x16_bf16(ones8, pfB0, laccB, 0, 0, 0);
#pragma unroll
      for (int hb = 0; hb < 2; ++hb) {
        short8 vf = *(const short8*)&vb[(hb * 32 + l31) * 64 + ((kblk * 4 + l5) ^ p7) * 8];
        if (hb == 0) {
          accA0 = __builtin_amdgcn_mfma_f32_32x32x16_bf16(vf, pfA0, accA0, 0, 0, 0);
          accB0 = __builtin_amdgcn_mfma_f32_32x32x16_bf16(vf, pfB0, accB0, 0, 0, 0);
        } else {
          accA1 = __builtin_amdgcn_mfma_f32_32x32x16_bf16(vf, pfA0, accA1, 0, 0, 0);
          accB1 = __builtin_amdgcn_mfma_f32_32x32x16_bf16(vf, pfB0, accB1, 0, 0, 0);
        }
      }
      laccA = __builtin_amdgcn_mfma_f32_32x32x16_bf16(ones8, pfA1, laccA, 0, 0, 0);
      laccB = __builtin_amdgcn_mfma_f32_32x32x16_bf16(ones8, pfB1, laccB, 0, 0, 0);
#pragma unroll
      for (int hb = 0; hb < 2; ++hb) {
        short8 vf = *(const short8*)&vb[(hb * 32 + l31) * 64 + ((kblk * 4 + 2 + l5) ^ p7) * 8];
        if (hb == 0) {
          accA0 = __builtin_amdgcn_mfma_f32_32x32x16_bf16(vf, pfA1, accA0, 0, 0, 0);
          accB0 = __builtin_amdgcn_mfma_f32_32x32x16_bf16(vf, pfB1, accB0, 0, 0, 0);
        } else {
          accA1 = __builtin_amdgcn_mfma_f32_32x32x16_bf16(vf, pfA1, accA1, 0, 0, 0);
          accB1 = __builtin_amdgcn_mfma_f32_32x32x16_bf16(vf, pfB1, accB1, 0, 0, 0);
        }
      }
      __builtin_amdgcn_s_setprio(0);
    }
    __syncthreads();  // drains prefetch + protects buffers for c+2 staging
  }
#undef SOFTMAX32

  // ---- epilogue: l comes straight from the ones-MFMA accumulator (all rows
  // equal, lane halves agree) — no cross-lane reduction needed ----
  {
    float inv = 1.f / laccA[0];
    int q = qt * 256 + w * 64 + l31;
    size_t base = ((size_t)b * S_LEN + q) * 2048 + h * 64;
#pragma unroll
    for (int rq = 0; rq < 4; ++rq) {
      u16x4 o0, o1;
#pragma unroll
      for (int rr = 0; rr < 4; ++rr) {
        o0[rr] = f2bf(accA0[rq * 4 + rr] * inv);
        o1[rr] = f2bf(accA1[rq * 4 + rr] * inv);
      }
      *(u16x4*)&Ao[base + rq * 8 + l5 * 4] = o0;
      *(u16x4*)&Ao[base + 32 + rq * 8 + l5 * 4] = o1;
    }
  }
  {
    float inv = 1.f / laccB[0];
    int q = qt * 256 + w * 64 + 32 + l31;
    size_t base = ((size_t)b * S_LEN + q) * 2048 + h * 64;
#pragma unroll
    for (int rq = 0; rq < 4; ++rq) {
      u16x4 o0, o1;
#pragma unroll
      for (int rr = 0; rr < 4; ++rr) {
        o0[rr] = f2bf(accB0[rq * 4 + rr] * inv);
        o1[rr] = f2bf(accB1[rq * 4 + rr] * inv);
      }
      *(u16x4*)&Ao[base + rq * 8 + l5 * 4] = o0;
      *(u16x4*)&Ao[base + 32 + rq * 8 + l5 * 4] = o1;
    }
  }
}

extern "C" void kernel_launch(void* const* d_in, const int* in_sizes, int n_in,
                              void* d_out, int out_size, void* d_ws, size_t ws_size,
                              hipStream_t stream) {
  const float* X  = (const float*)d_in[0];
  const float* Wq = (const float*)d_in[1];
  const float* Wk = (const float*)d_in[2];
  const float* Wv = (const float*)d_in[3];
  const float* Wo = (const float*)d_in[4];
  char* ws = (char*)d_ws;
  u16* Xb  = (u16*)(ws);                  // 16 MB  [4096][2048]
  u16* Wqt = (u16*)(ws + 16777216);       //  8 MB  [2048][2048]
  u16* Wkt = (u16*)(ws + 25165824);       //  2 MB  [512][2048]   (K rows)
  u16* Wvt = (u16*)(ws + 27262976);       //  2 MB  [512][2048]   (V rows, contiguous after K)
  u16* Wot = (u16*)(ws + 29360128);       //  8 MB  [2048][2048]
  u16* Qb  = (u16*)(ws + 37748736);       // 16 MB  [B,H,S,64]
  u16* Kb  = (u16*)(ws + 54525952);       //  4 MB  [B,KVH,S,64]; VT at Kb+2097152 u16
  u16* VTb = (u16*)(ws + 58720256);       //  4 MB  [B,KVH,64,S]
  u16* Ab  = (u16*)(ws + 62914560);       // 16 MB  [4096][2048]
  float* out = (float*)d_out;

  prep_kernel<<<18432, 256, 0, stream>>>(X, Wq, Wk, Wv, Wo, Xb, Wqt, Wkt, Wvt, Wot);
  gemm_qkv<<<768, 256, 0, stream>>>(Xb, Wqt, Wkt, Qb, Kb);
  attn_kernel<<<512, 256, 0, stream>>>(Qb, Kb, VTb, Ab);
  gemm_out<<<512, 256, 0, stream>>>(Ab, Wot, out);
}